// Round 1
// baseline (330.324 us; speedup 1.0000x reference)
//
#include <hip/hip_runtime.h>

// LabelWiseMLC: out[b,l] = sigmoid(dot(doc_rep[b,l,:], W[l,:]) + bias[l])
// B=128, L=512, I=1024, fp32. Memory-bound: doc (268 MB) streamed once.
// Roofline: 268 MB / 6.3 TB/s ~= 43 us.
//
// Label-stationary waves: each wave owns one label l and WPB=8 batch rows.
// W[l] (4 KiB) loaded once into 16 VGPRs, reused across 8 dots.
//
// v2 restructure (vs 332us v1):
//  - streaming phase is loads+FMA only; ALL cross-lane reduction deferred
//    to after the loop (v1 ran 6 dependent bpermutes per row inside the
//    load loop -> memory pipe idle during reduce tails)
//  - explicit 4-row pipeline buf[4][4]: 16 dwordx4 loads in flight per
//    wave at all times (v1 unroll-2 capped at 8, drained each block)
//  - folded butterfly: 8 row-sums reduced with 10 shfl_xor total
//    (fold 8->4->2->1 over xor 32/16/8, then xor 4/2/1), results land on
//    lanes 0,8,..,56 -> single 8-lane store instruction
//  - __launch_bounds__(256,4): pin <=128 VGPR so 16 waves/CU resident

#define B_DIM 128
#define L_DIM 512
#define I_DIM 1024
#define WPB 8    // batch rows per wave
#define DEPTH 4  // pipelined rows in flight

typedef float vfloat4 __attribute__((ext_vector_type(4)));

__global__ __launch_bounds__(256, 4) void labelwise_mlc_kernel(
    const float* __restrict__ doc,   // (B, L, I)
    const float* __restrict__ W,     // (L, I)
    const float* __restrict__ bias,  // (L,)
    float* __restrict__ out)         // (B, L)
{
    const int wave = (blockIdx.x * 256 + threadIdx.x) >> 6;  // 0..8191
    const int lane = threadIdx.x & 63;
    const int l  = wave & (L_DIM - 1);          // label index
    const int b0 = (wave >> 9) * WPB;           // starting batch row

    // W[l] fragment: lane i holds float4s at {i, 64+i, 128+i, 192+i}
    const vfloat4* __restrict__ wp = (const vfloat4*)(W + (size_t)l * I_DIM);
    vfloat4 w[4];
#pragma unroll
    for (int k = 0; k < 4; ++k) w[k] = wp[lane + 64 * k];
    const float bl = bias[l];

    const float* dbase = doc + ((size_t)b0 * L_DIM + l) * I_DIM;
    const size_t rstride = (size_t)L_DIM * I_DIM;  // floats between b rows

    // ---- streaming phase: pure loads + per-lane FMA partials ----
    vfloat4 buf[DEPTH][4];
#pragma unroll
    for (int j = 0; j < DEPTH; ++j) {
        const vfloat4* dp = (const vfloat4*)(dbase + (size_t)j * rstride);
#pragma unroll
        for (int k = 0; k < 4; ++k)
            buf[j][k] = __builtin_nontemporal_load(dp + lane + 64 * k);
    }

    float acc[WPB];
#pragma unroll
    for (int j = 0; j < WPB; ++j) {
        const int s = j & (DEPTH - 1);  // compile-time after unroll
        float a0 = 0.0f, a1 = 0.0f;     // two chains: halve FMA latency
#pragma unroll
        for (int k = 0; k < 2; ++k) {
            a0 = fmaf(buf[s][k].x, w[k].x, a0);
            a0 = fmaf(buf[s][k].y, w[k].y, a0);
            a0 = fmaf(buf[s][k].z, w[k].z, a0);
            a0 = fmaf(buf[s][k].w, w[k].w, a0);
        }
#pragma unroll
        for (int k = 2; k < 4; ++k) {
            a1 = fmaf(buf[s][k].x, w[k].x, a1);
            a1 = fmaf(buf[s][k].y, w[k].y, a1);
            a1 = fmaf(buf[s][k].z, w[k].z, a1);
            a1 = fmaf(buf[s][k].w, w[k].w, a1);
        }
        acc[j] = a0 + a1;
        if (j + DEPTH < WPB) {  // refill slot s with row j+DEPTH
            const vfloat4* dp =
                (const vfloat4*)(dbase + (size_t)(j + DEPTH) * rstride);
#pragma unroll
            for (int k = 0; k < 4; ++k)
                buf[s][k] = __builtin_nontemporal_load(dp + lane + 64 * k);
        }
    }

    // ---- folded multi-row butterfly reduction: 10 shuffles total ----
    // stage A (xor 32): fold 8 -> 4. lanes bit5=0 own j in [0,4),
    // bit5=1 own j in [4,8) (stored in slots [0,4)).
    const bool hi5 = (lane & 32) != 0;
    float r[4];
#pragma unroll
    for (int i = 0; i < 4; ++i) {
        const float mine = hi5 ? acc[i + 4] : acc[i];
        const float send = hi5 ? acc[i] : acc[i + 4];
        r[i] = mine + __shfl_xor(send, 32, 64);
    }
    // stage B (xor 16): fold 4 -> 2. bit4 adds +2 to owned j.
    const bool hi4 = (lane & 16) != 0;
    float s2[2];
#pragma unroll
    for (int i = 0; i < 2; ++i) {
        const float mine = hi4 ? r[i + 2] : r[i];
        const float send = hi4 ? r[i] : r[i + 2];
        s2[i] = mine + __shfl_xor(send, 16, 64);
    }
    // stage C (xor 8): fold 2 -> 1. bit3 adds +1 to owned j.
    const bool hi3 = (lane & 8) != 0;
    {
        const float mine = hi3 ? s2[1] : s2[0];
        const float send = hi3 ? s2[0] : s2[1];
        s2[0] = mine + __shfl_xor(send, 8, 64);
    }
    // stages D (xor 4,2,1): finish the 8-lane group sum.
    s2[0] += __shfl_xor(s2[0], 4, 64);
    s2[0] += __shfl_xor(s2[0], 2, 64);
    s2[0] += __shfl_xor(s2[0], 1, 64);

    // lane 8m holds S[j=m] (m = 4*bit5 + 2*bit4 + 1*bit3 = lane>>3).
    if ((lane & 7) == 0) {
        const int j = lane >> 3;
        const float v = s2[0] + bl;
        out[(size_t)(b0 + j) * L_DIM + l] = 1.0f / (1.0f + __expf(-v));
    }
}

extern "C" void kernel_launch(void* const* d_in, const int* in_sizes, int n_in,
                              void* d_out, int out_size, void* d_ws, size_t ws_size,
                              hipStream_t stream) {
    const float* doc  = (const float*)d_in[0];  // (128, 512, 1024)
    const float* W    = (const float*)d_in[1];  // (512, 1024)
    const float* bias = (const float*)d_in[2];  // (512,)
    float* out = (float*)d_out;                 // (128, 512)

    // 8192 waves: 512 labels x 16 wave-groups (8 batch rows each)
    const int blocks = (L_DIM * (B_DIM / WPB)) / 4;  // 2048
    labelwise_mlc_kernel<<<blocks, 256, 0, stream>>>(doc, W, bias, out);
}